// Round 7
// baseline (148.349 us; speedup 1.0000x reference)
//
#include <hip/hip_runtime.h>
#include <math.h>

#define SLICES 32
#define ROWS_PER_SLICE 16
#define NBOXES 160
#define THREADS 256

static __device__ __forceinline__ float fast_sigmoid(float x) {
    return __builtin_amdgcn_rcpf(1.0f + __expf(-x));
}

// One block per (slice, batch). ZERO LDS, ZERO __syncthreads in the hot path:
// each lane accumulates the 8 4-bit mask nibbles it needs (rows rb+2k, cols
// 4*col4..4*col4+3) directly in registers during the readlane box scan, so
// the 8 prefetched pred float4 stay in flight underneath (no barrier ever
// forces vmcnt(0)). Per-wave partials go straight to global.
__global__ __launch_bounds__(THREADS, 6) void paint_reduce_kernel(
    const float* __restrict__ pred, const int* __restrict__ targets,
    float* __restrict__ partials)
{
    const int t = threadIdx.x;
    const int slice = blockIdx.x;
    const int b = blockIdx.y;
    const int r0 = slice * ROWS_PER_SLICE;
    const int lane = t & 63, wave = t >> 6;
    const int col4 = t & 127;
    const int rb = t >> 7;  // 0 or 1; rows handled: r0 + rb + 2k, k=0..7
    const int c0 = col4 * 4;  // first column this lane covers (4 columns)

    // ---- Issue box loads first (FIFO: they complete before pred). ----
    const int4* tg = (const int4*)targets + (size_t)b * NBOXES;
    int4 gb0 = tg[lane];
    int4 gb1 = tg[64 + lane];
    int4 gb2 = (lane < 32) ? tg[128 + lane] : make_int4(0, 0, 0, 0);

    // ---- Issue all 8 pred float4; they drain during the box scan. ----
    const float4* p4 = (const float4*)pred;
    const size_t g0 = (size_t)b * 65536 + (size_t)(r0 + rb) * 128 + col4;
    float4 v0 = p4[g0 + 0 * 256];
    float4 v1 = p4[g0 + 1 * 256];
    float4 v2 = p4[g0 + 2 * 256];
    float4 v3 = p4[g0 + 3 * 256];
    float4 v4 = p4[g0 + 4 * 256];
    float4 v5 = p4[g0 + 5 * 256];
    float4 v6 = p4[g0 + 6 * 256];
    float4 v7 = p4[g0 + 7 * 256];

    // ---- Clip boxes to this slice; ballot the survivors. ----
    unsigned px0, py0, px1, py1, px2, py2;
    auto clip = [&](int4 g, unsigned& px, unsigned& py) -> bool {
        int x1 = min(g.x, 512), y1 = min(g.y, 512);
        int x2 = min(g.x + g.z, 512), y2 = min(g.y + g.w, 512);
        int cx1 = max(x1, r0), cx2 = min(x2, r0 + ROWS_PER_SLICE);
        px = (unsigned)cx1 | ((unsigned)cx2 << 16);
        py = (unsigned)y1 | ((unsigned)y2 << 16);
        return (cx2 > cx1) && (y2 > y1);
    };
    bool k0 = clip(gb0, px0, py0);
    bool k1 = clip(gb1, px1, py1);
    bool k2 = clip(gb2, px2, py2) && (lane < 32);
    unsigned long long bm0 = __ballot(k0);
    unsigned long long bm1 = __ballot(k1);
    unsigned long long bm2 = __ballot(k2);

    // ---- Scan survivors via readlane; accumulate 8 per-lane nibbles. ----
    unsigned m[8] = {0, 0, 0, 0, 0, 0, 0, 0};
    auto scan = [&](unsigned long long mk, unsigned px, unsigned py) {
        while (mk) {
            int k = (int)__builtin_ctzll(mk);
            mk &= mk - 1;
            unsigned rx = (unsigned)__builtin_amdgcn_readlane((int)px, k);
            unsigned ry = (unsigned)__builtin_amdgcn_readlane((int)py, k);
            const int x1 = (int)(rx & 0xffffu), x2 = (int)(rx >> 16);
            const int y1 = (int)(ry & 0xffffu), y2 = (int)(ry >> 16);
            // Column window [c0, c0+4) vs [y1, y2): 4-bit nibble.
            int lo = max(y1, c0), hi = min(y2, c0 + 4);
            int nn = hi - lo;
            unsigned nibw = (nn > 0) ? (((1u << nn) - 1u) << (lo - c0)) : 0u;
            // Row tests are wave-uniform (r0, rb, x1, x2 all uniform).
#pragma unroll
            for (int kk = 0; kk < 8; ++kk) {
                const int r = r0 + rb + 2 * kk;
                m[kk] |= (r >= x1 && r < x2) ? nibw : 0u;
            }
        }
    };
    scan(bm0, px0, py0);
    scan(bm1, px1, py1);
    scan(bm2, px2, py2);

    // ---- Consume the pred loads (vmcnt waits interleave naturally). ----
    float psum = 0.0f, isum = 0.0f;
    int cnt = 0;
#define ACC(V, N)                                                       \
    {                                                                   \
        float s0 = fast_sigmoid((V).x);                                 \
        float s1 = fast_sigmoid((V).y);                                 \
        float s2 = fast_sigmoid((V).z);                                 \
        float s3 = fast_sigmoid((V).w);                                 \
        psum += (s0 + s1) + (s2 + s3);                                  \
        cnt += __popc(N);                                               \
        isum += (((N) & 1u) ? s0 : 0.0f) + (((N) & 2u) ? s1 : 0.0f)     \
              + (((N) & 4u) ? s2 : 0.0f) + (((N) & 8u) ? s3 : 0.0f);    \
    }
    ACC(v0, m[0]) ACC(v1, m[1]) ACC(v2, m[2]) ACC(v3, m[3])
    ACC(v4, m[4]) ACC(v5, m[5]) ACC(v6, m[6]) ACC(v7, m[7])
#undef ACC
    float csum = (float)cnt;

    // ---- Wave reduce; lane 0 writes the wave's partial to global. ----
    for (int off = 32; off > 0; off >>= 1) {
        psum += __shfl_down(psum, off);
        isum += __shfl_down(isum, off);
        csum += __shfl_down(csum, off);
    }
    if (lane == 0) {
        float* o = partials + (((size_t)b * SLICES + slice) * 4 + wave) * 3;
        o[0] = psum; o[1] = isum; o[2] = csum;
    }
}

// One lane per batch folds 32 slices x 4 waves of partials.
__global__ __launch_bounds__(64) void final_kernel(
    const float* __restrict__ partials, float* __restrict__ out)
{
    const int b = threadIdx.x;  // 0..63
    double P = 0, I = 0, C = 0;
    const float* p = partials + (size_t)b * SLICES * 4 * 3;
    for (int s = 0; s < SLICES * 4; ++s) {
        P += (double)p[s * 3 + 0];
        I += (double)p[s * 3 + 1];
        C += (double)p[s * 3 + 2];
    }
    const double inter = 255.0 * I;
    const double tsum  = 255.0 * C;
    double loss = (inter + 1.0) / (P + tsum - inter + 1.0);
    for (int off = 32; off > 0; off >>= 1) loss += __shfl_down(loss, off);
    if (b == 0) out[0] = (float)(1.0 - loss / 64.0);
}

extern "C" void kernel_launch(void* const* d_in, const int* in_sizes, int n_in,
                              void* d_out, int out_size, void* d_ws, size_t ws_size,
                              hipStream_t stream) {
    const float* pred    = (const float*)d_in[0];  // (64,1,512,512) f32
    const int*   targets = (const int*)d_in[1];    // (64,5,32,4) i32
    float* out = (float*)d_out;                    // 1 f32 scalar
    float* partials = (float*)d_ws;                // 64*32*4*3 f32 = 96 KiB

    dim3 grid(SLICES, 64);
    paint_reduce_kernel<<<grid, THREADS, 0, stream>>>(pred, targets, partials);
    final_kernel<<<1, 64, 0, stream>>>(partials, out);
}

// Round 8
// 112.979 us; speedup vs baseline: 1.3131x; 1.3131x over previous
//
#include <hip/hip_runtime.h>
#include <math.h>

#define SLICES 32
#define ROWS_PER_SLICE 16
#define NBOXES 160

static __device__ __forceinline__ float fast_sigmoid(float x) {
    return __builtin_amdgcn_rcpf(1.0f + __expf(-x));
}

// K1: build painted-pixel bitmask into global. grid (SLICES,64) x 256.
// Thread t = (row t>>4, word t&15). Box list ballot-compacted into LDS as
// packed uint2; scan loop reads uniform LDS addresses (ds_read_b64 hardware
// broadcast — no readlane, no waterfall risk, no spill pressure).
__global__ __launch_bounds__(256) void mask_kernel(
    const int* __restrict__ targets, unsigned* __restrict__ gmask)
{
    __shared__ uint2 s_box[NBOXES];
    __shared__ int s_wcnt[4];

    const int t = threadIdx.x;
    const int slice = blockIdx.x;
    const int b = blockIdx.y;
    const int r0 = slice * ROWS_PER_SLICE;
    const int lane = t & 63, wave = t >> 6;

    // Load + clip + ballot-compact (threads 0..159 carry boxes).
    bool keep = false;
    unsigned px = 0, py = 0;
    if (t < NBOXES) {
        const int4 g = ((const int4*)targets)[(size_t)b * NBOXES + t];
        int x1 = min(g.x, 512), y1 = min(g.y, 512);
        int x2 = min(g.x + g.z, 512), y2 = min(g.y + g.w, 512);
        int cx1 = max(x1, r0), cx2 = min(x2, r0 + ROWS_PER_SLICE);
        px = (unsigned)cx1 | ((unsigned)cx2 << 16);
        py = (unsigned)y1 | ((unsigned)y2 << 16);
        keep = (cx2 > cx1) && (y2 > y1);
    }
    const unsigned long long bal = __ballot(keep);
    if (lane == 0) s_wcnt[wave] = (int)__popcll(bal);
    __syncthreads();
    int wbase = 0;
    for (int w = 0; w < wave; ++w) wbase += s_wcnt[w];
    const int nb = s_wcnt[0] + s_wcnt[1] + s_wcnt[2] + s_wcnt[3];
    if (keep) {
        const int idx = wbase + (int)__popcll(bal & ((1ull << lane) - 1ull));
        s_box[idx] = make_uint2(px, py);
    }
    __syncthreads();

    // Scan: uniform-index LDS broadcast loop, ~9 VALU/box.
    const int r = r0 + (t >> 4);
    const unsigned wb = (unsigned)(t & 15) * 32u;
    unsigned m = 0;
#pragma unroll 2
    for (int k = 0; k < nb; ++k) {
        const uint2 bx = s_box[k];
        const int x1 = (int)(bx.x & 0xffffu), x2 = (int)(bx.x >> 16);
        const int y1 = (int)(bx.y & 0xffffu), y2 = (int)(bx.y >> 16);
        const bool in_row = (r >= x1) && (r < x2);
        int lo = max(y1, (int)wb), hi = min(y2, (int)wb + 32);
        int nn = hi - lo;
        unsigned bits = 0xFFFFFFFFu >> ((32 - nn) & 31);
        unsigned contrib = bits << ((unsigned)(lo - (int)wb) & 31u);
        m |= (in_row && nn > 0) ? contrib : 0u;
    }
    // Coalesced: 256 consecutive dwords per block.
    gmask[(size_t)b * 8192 + (size_t)r0 * 16 + t] = m;
}

// K2: pure streaming — zero LDS, zero barriers, no spill (VGPR cap 128).
// 16 loads issued up front (8 mask dwords + 8 float4), sigmoid + masked
// accumulate, per-wave partials straight to global.
__global__ __launch_bounds__(256, 4) void stream_kernel(
    const float* __restrict__ pred, const unsigned* __restrict__ gmask,
    float* __restrict__ partials)
{
    const int t = threadIdx.x;
    const int slice = blockIdx.x;
    const int b = blockIdx.y;
    const int r0 = slice * ROWS_PER_SLICE;
    const int lane = t & 63, wave = t >> 6;
    const int col4 = t & 127;
    const int rb = t >> 7;  // 0/1; rows handled: r0 + rb + 2k, k=0..7
    const int widx = col4 >> 3;
    const unsigned bb = (unsigned)(col4 & 7) * 4u;

    const unsigned* gm = gmask + (size_t)b * 8192 + (size_t)(r0 + rb) * 16 + widx;
    unsigned w0 = gm[0 * 32];
    unsigned w1 = gm[1 * 32];
    unsigned w2 = gm[2 * 32];
    unsigned w3 = gm[3 * 32];
    unsigned w4 = gm[4 * 32];
    unsigned w5 = gm[5 * 32];
    unsigned w6 = gm[6 * 32];
    unsigned w7 = gm[7 * 32];

    const float4* p4 = (const float4*)pred;
    const size_t g0 = (size_t)b * 65536 + (size_t)(r0 + rb) * 128 + col4;
    float4 v0 = p4[g0 + 0 * 256];
    float4 v1 = p4[g0 + 1 * 256];
    float4 v2 = p4[g0 + 2 * 256];
    float4 v3 = p4[g0 + 3 * 256];
    float4 v4 = p4[g0 + 4 * 256];
    float4 v5 = p4[g0 + 5 * 256];
    float4 v6 = p4[g0 + 6 * 256];
    float4 v7 = p4[g0 + 7 * 256];

    float psum = 0.0f, isum = 0.0f;
    int cnt = 0;
#define ACC(V, W)                                                       \
    {                                                                   \
        const unsigned n = ((W) >> bb) & 0xFu;                          \
        float s0 = fast_sigmoid((V).x);                                 \
        float s1 = fast_sigmoid((V).y);                                 \
        float s2 = fast_sigmoid((V).z);                                 \
        float s3 = fast_sigmoid((V).w);                                 \
        psum += (s0 + s1) + (s2 + s3);                                  \
        cnt += __popc(n);                                               \
        isum += ((n & 1u) ? s0 : 0.0f) + ((n & 2u) ? s1 : 0.0f)         \
              + ((n & 4u) ? s2 : 0.0f) + ((n & 8u) ? s3 : 0.0f);        \
    }
    ACC(v0, w0) ACC(v1, w1) ACC(v2, w2) ACC(v3, w3)
    ACC(v4, w4) ACC(v5, w5) ACC(v6, w6) ACC(v7, w7)
#undef ACC
    float csum = (float)cnt;

    for (int off = 32; off > 0; off >>= 1) {
        psum += __shfl_down(psum, off);
        isum += __shfl_down(isum, off);
        csum += __shfl_down(csum, off);
    }
    if (lane == 0) {
        float* o = partials + (((size_t)b * SLICES + slice) * 4 + wave) * 3;
        o[0] = psum; o[1] = isum; o[2] = csum;
    }
}

// K3: one lane per batch folds 32 slices x 4 waves of partials.
__global__ __launch_bounds__(64) void final_kernel(
    const float* __restrict__ partials, float* __restrict__ out)
{
    const int b = threadIdx.x;  // 0..63
    double P = 0, I = 0, C = 0;
    const float* p = partials + (size_t)b * SLICES * 4 * 3;
    for (int s = 0; s < SLICES * 4; ++s) {
        P += (double)p[s * 3 + 0];
        I += (double)p[s * 3 + 1];
        C += (double)p[s * 3 + 2];
    }
    const double inter = 255.0 * I;
    const double tsum  = 255.0 * C;
    double loss = (inter + 1.0) / (P + tsum - inter + 1.0);
    for (int off = 32; off > 0; off >>= 1) loss += __shfl_down(loss, off);
    if (b == 0) out[0] = (float)(1.0 - loss / 64.0);
}

extern "C" void kernel_launch(void* const* d_in, const int* in_sizes, int n_in,
                              void* d_out, int out_size, void* d_ws, size_t ws_size,
                              hipStream_t stream) {
    const float* pred    = (const float*)d_in[0];  // (64,1,512,512) f32
    const int*   targets = (const int*)d_in[1];    // (64,5,32,4) i32
    float* out = (float*)d_out;                    // 1 f32 scalar

    // ws layout: [0, 96 KiB) per-wave partials; [96 KiB, +2 MiB) bitmask.
    float* partials = (float*)d_ws;                          // 64*32*4*3 f32
    unsigned* gmask = (unsigned*)((char*)d_ws + (96 << 10)); // 64*8192 u32

    dim3 grid(SLICES, 64);
    mask_kernel<<<grid, 256, 0, stream>>>(targets, gmask);
    stream_kernel<<<grid, 256, 0, stream>>>(pred, gmask, partials);
    final_kernel<<<1, 64, 0, stream>>>(partials, out);
}

// Round 10
// 108.842 us; speedup vs baseline: 1.3630x; 1.0380x over previous
//
#include <hip/hip_runtime.h>
#include <math.h>

#define SLICES 32
#define ROWS_PER_SLICE 16
#define NBOXES 160
#define THREADS 256

static __device__ __forceinline__ float fast_sigmoid(float x) {
    return __builtin_amdgcn_rcpf(1.0f + __expf(-x));
}

// Fused: one block per (slice, batch).
// The 8 pred float4 loads are issued as raw asm global_load_dwordx4 with
// distinct "=v" outputs, so the register allocator MUST keep 8 loads
// outstanding per thread (R7's VGPR=36 proved the compiler otherwise sinks
// each load to its use => ~1 outstanding => ~1.8 TB/s => the ~35us floor).
// The compiler cannot see these loads, so the ONLY wait that guarantees the
// data has landed is the explicit plain s_waitcnt vmcnt(0) before ACC
// (plain, untied: tied float4 operands don't compile on gfx950).
__global__ __launch_bounds__(THREADS, 4) void paint_reduce_kernel(
    const float* __restrict__ pred, const int* __restrict__ targets,
    float* __restrict__ partials)
{
    __shared__ uint2 s_box[192];      // 3 segments x 64 (per-wave compaction)
    __shared__ int s_wcnt[3];
    __shared__ unsigned s_mask[256];  // 16 rows x 16 words = 512 bits/row

    const int t = threadIdx.x;
    const int slice = blockIdx.x;
    const int b = blockIdx.y;
    const int r0 = slice * ROWS_PER_SLICE;
    const int lane = t & 63, wave = t >> 6;
    const int col4 = t & 127;
    const int rb = t >> 7;  // 0/1; rows handled: r0 + rb + 2k, k=0..7

    // ---- Box load first (tracked load; compiler inserts its own wait). ----
    int4 g = make_int4(0, 0, 0, 0);
    if (t < NBOXES) g = ((const int4*)targets)[(size_t)b * NBOXES + t];

    // ---- Issue 8 pred loads as pinned asm; they stay in flight through
    //      the whole box/mask phase. ----
    const float4* p4 = (const float4*)pred + (size_t)b * 65536
                     + (size_t)(r0 + rb) * 128 + col4;
    float4 v0, v1, v2, v3, v4, v5, v6, v7;
    asm volatile("global_load_dwordx4 %0, %1, off" : "=v"(v0) : "v"(p4 + 0 * 256));
    asm volatile("global_load_dwordx4 %0, %1, off" : "=v"(v1) : "v"(p4 + 1 * 256));
    asm volatile("global_load_dwordx4 %0, %1, off" : "=v"(v2) : "v"(p4 + 2 * 256));
    asm volatile("global_load_dwordx4 %0, %1, off" : "=v"(v3) : "v"(p4 + 3 * 256));
    asm volatile("global_load_dwordx4 %0, %1, off" : "=v"(v4) : "v"(p4 + 4 * 256));
    asm volatile("global_load_dwordx4 %0, %1, off" : "=v"(v5) : "v"(p4 + 5 * 256));
    asm volatile("global_load_dwordx4 %0, %1, off" : "=v"(v6) : "v"(p4 + 6 * 256));
    asm volatile("global_load_dwordx4 %0, %1, off" : "=v"(v7) : "v"(p4 + 7 * 256));

    // ---- Clip + per-wave segmented compaction (no cross-wave prefix). ----
    bool keep = false;
    unsigned px = 0, py = 0;
    if (t < NBOXES) {
        int x1 = min(g.x, 512), y1 = min(g.y, 512);
        int x2 = min(g.x + g.z, 512), y2 = min(g.y + g.w, 512);
        int cx1 = max(x1, r0), cx2 = min(x2, r0 + ROWS_PER_SLICE);
        px = (unsigned)cx1 | ((unsigned)cx2 << 16);
        py = (unsigned)y1 | ((unsigned)y2 << 16);
        keep = (cx2 > cx1) && (y2 > y1);
    }
    const unsigned long long bal = __ballot(keep);
    if (wave < 3 && lane == 0) s_wcnt[wave] = (int)__popcll(bal);
    if (keep) {
        const int idx = (int)__popcll(bal & ((1ull << lane) - 1ull));
        s_box[wave * 64 + idx] = make_uint2(px, py);
    }
    __syncthreads();   // barrier #1

    // ---- Mask scan: uniform-index LDS broadcast, ~10 VALU/box. ----
    const int r = r0 + (t >> 4);
    const int wbase = (t & 15) * 32;
    unsigned m = 0;
    for (int w = 0; w < 3; ++w) {
        const int nb = s_wcnt[w];
        for (int k = 0; k < nb; ++k) {
            const uint2 bx = s_box[w * 64 + k];
            const int x1 = (int)(bx.x & 0xffffu), x2 = (int)(bx.x >> 16);
            const int y1 = (int)(bx.y & 0xffffu), y2 = (int)(bx.y >> 16);
            const bool in_row = (r >= x1) && (r < x2);
            int lo = max(y1, wbase), hi = min(y2, wbase + 32);
            int nn = hi - lo;
            unsigned bits = 0xFFFFFFFFu >> ((32 - nn) & 31);
            unsigned contrib = bits << ((unsigned)(lo - wbase) & 31u);
            m |= (in_row && nn > 0) ? contrib : 0u;
        }
    }
    s_mask[t] = m;
    __syncthreads();   // barrier #2

    // ---- Read the 8 mask words this lane needs. ----
    const int widx = col4 >> 3;
    const unsigned bb = (unsigned)(col4 & 7) * 4u;
    unsigned w0 = s_mask[(rb +  0) * 16 + widx];
    unsigned w1 = s_mask[(rb +  2) * 16 + widx];
    unsigned w2 = s_mask[(rb +  4) * 16 + widx];
    unsigned w3 = s_mask[(rb +  6) * 16 + widx];
    unsigned w4 = s_mask[(rb +  8) * 16 + widx];
    unsigned w5 = s_mask[(rb + 10) * 16 + widx];
    unsigned w6 = s_mask[(rb + 12) * 16 + widx];
    unsigned w7 = s_mask[(rb + 14) * 16 + widx];

    // The one wait that makes the asm loads' data valid. Consumption below
    // lives in post-loop blocks, so it cannot be scheduled above this.
    asm volatile("s_waitcnt vmcnt(0)" ::: "memory");

    float psum = 0.0f, isum = 0.0f;
    int cnt = 0;
#define ACC(V, W)                                                       \
    {                                                                   \
        const unsigned n = ((W) >> bb) & 0xFu;                          \
        float s0 = fast_sigmoid((V).x);                                 \
        float s1 = fast_sigmoid((V).y);                                 \
        float s2 = fast_sigmoid((V).z);                                 \
        float s3 = fast_sigmoid((V).w);                                 \
        psum += (s0 + s1) + (s2 + s3);                                  \
        cnt += __popc(n);                                               \
        isum += ((n & 1u) ? s0 : 0.0f) + ((n & 2u) ? s1 : 0.0f)         \
              + ((n & 4u) ? s2 : 0.0f) + ((n & 8u) ? s3 : 0.0f);        \
    }
    ACC(v0, w0) ACC(v1, w1) ACC(v2, w2) ACC(v3, w3)
    ACC(v4, w4) ACC(v5, w5) ACC(v6, w6) ACC(v7, w7)
#undef ACC
    float csum = (float)cnt;

    // ---- Wave reduce; lane 0 writes the wave's partial (SoA layout). ----
    for (int off = 32; off > 0; off >>= 1) {
        psum += __shfl_down(psum, off);
        isum += __shfl_down(isum, off);
        csum += __shfl_down(csum, off);
    }
    if (lane == 0) {
        const size_t idx = ((size_t)b * SLICES + slice) * 4 + wave;
        partials[idx]         = psum;   // P block: [0, 8192)
        partials[8192 + idx]  = isum;   // I block: [8192, 16384)
        partials[16384 + idx] = csum;   // C block: [16384, 24576)
    }
}

// One lane per batch; SoA partials allow float4 loads (32 per array).
__global__ __launch_bounds__(64) void final_kernel(
    const float* __restrict__ partials, float* __restrict__ out)
{
    const int b = threadIdx.x;  // 0..63
    const float4* P4 = (const float4*)(partials)         + b * 32;
    const float4* I4 = (const float4*)(partials + 8192)  + b * 32;
    const float4* C4 = (const float4*)(partials + 16384) + b * 32;
    double P = 0, I = 0, C = 0;
    for (int j = 0; j < 32; ++j) {
        float4 p = P4[j]; P += (double)p.x + p.y + p.z + p.w;
        float4 i = I4[j]; I += (double)i.x + i.y + i.z + i.w;
        float4 c = C4[j]; C += (double)c.x + c.y + c.z + c.w;
    }
    const double inter = 255.0 * I;
    const double tsum  = 255.0 * C;
    double loss = (inter + 1.0) / (P + tsum - inter + 1.0);
    for (int off = 32; off > 0; off >>= 1) loss += __shfl_down(loss, off);
    if (b == 0) out[0] = (float)(1.0 - loss / 64.0);
}

extern "C" void kernel_launch(void* const* d_in, const int* in_sizes, int n_in,
                              void* d_out, int out_size, void* d_ws, size_t ws_size,
                              hipStream_t stream) {
    const float* pred    = (const float*)d_in[0];  // (64,1,512,512) f32
    const int*   targets = (const int*)d_in[1];    // (64,5,32,4) i32
    float* out = (float*)d_out;                    // 1 f32 scalar
    float* partials = (float*)d_ws;                // 3 x 8192 f32 = 96 KiB

    dim3 grid(SLICES, 64);
    paint_reduce_kernel<<<grid, THREADS, 0, stream>>>(pred, targets, partials);
    final_kernel<<<1, 64, 0, stream>>>(partials, out);
}